// Round 7
// baseline (121.525 us; speedup 1.0000x reference)
//
#include <hip/hip_runtime.h>

#define NT 2000
#define NB 256
#define NF 5
#define NS 500
#define LOG0   (-1e30f)
#define LOG2E  1.44269504088896340736f
#define LN2F   0.69314718055994530942f
#define RSTRIDE 2024   // wtabT row stride: >=2000, %4==0 (b128 align), %32==8 (banks disjoint)

// One block per batch, 512 threads = 8 waves, 2 states/lane.
// Wave w spans states [64w-64, 64w+127]: lanes 0-31 = 64-state left halo
// (recomputed redundantly), lanes 32-63 = 64 owned states. Halo depth 64 =
// exchange period 64 (info moves right 1 state/step).
//
// R7: force-batch the chunk's 8 ds_read_b128 with sched_group_barrier.
// R6's VGPR=24 proved the compiler sank the hoisted loads back to their
// uses (a source-level hoist is not binding) -> reads dribble ds_read ->
// waitcnt -> 2 steps -> ds_read, exposing ~half of each ~100cy LDS latency
// even with 2 waves/SIMD covering. sched_group_barrier(DS_READ,8) pins the
// 8 reads as one contiguous batch WITHOUT R4's sched_barrier(0) freeze and
// WITHOUT carry copies (loads feed the current chunk directly, SSA). The
// waitcnt pass then emits counted lgkmcnt(7..0): reads 3-8 complete under
// the boundary code + early compute.
//
// Conditional renorm (R6, kept): rcp/log/exp2+DPP chain runs only when a
// live lane leaves [1e-12,1e12]; wave-uniform branch, adj stays valid when
// skipped. Exchange every 64 steps (log2 domain via Gbuf). XCD-swizzled
// batch id dedups the preamble gather in per-XCD L2 (FETCH 36->5.3MB).
// Exp-domain recurrence p[s] += p[s-1]*w_t[idx[s]] with per-lane log2
// scale Lw; cross-lane handoff via DPP wave_shr:1; adj = 2^(Lw_left-Lw)
// folded into the W0 operand off the dependent chain.
__device__ __forceinline__ float wave_shr1(float v) {
    // DPP wave_shr:1 (0x138): lane i reads lane i-1; bound_ctrl=1 -> lane 0 = 0.
    return __int_as_float(
        __builtin_amdgcn_mov_dpp(__float_as_int(v), 0x138, 0xf, 0xf, true));
}

__global__ __launch_bounds__(512, 1) void ctc_fwd_kernel(
    const float* __restrict__ x,        // (NT, NB, NF)
    const int*   __restrict__ seqs,     // (NB, NS)
    const int*   __restrict__ seqlens,  // (NB,)
    float*       __restrict__ out)      // (NB,)
{
    __shared__ __align__(16) float wtabT[4 * RSTRIDE];  // w[i][t] = exp(x_t[i]-x_t[4])
    __shared__ float Gbuf[576];                         // log2-domain exchange, idx = 64+s
    __shared__ float red[512];                          // stay-sum reduction

    // XCD-aware batch swizzle: hw round-robins blockIdx%8 across XCDs;
    // map so XCD k handles contiguous b in [32k, 32k+32) for L2 line sharing.
    const int b    = ((blockIdx.x & 7) << 5) | (blockIdx.x >> 3);
    const int tid  = threadIdx.x;
    const int wave = tid >> 6;
    const int lane = tid & 63;

    // ---------------- precompute: transposed weights + stay sum ----------------
    float csum = 0.f;
    for (int t = tid; t < NT; t += 512) {
        const float* xp = x + (size_t)t * (NB * NF) + b * NF;
        const float x4 = xp[4];
        wtabT[0 * RSTRIDE + t] = __builtin_amdgcn_exp2f((xp[0] - x4) * LOG2E);
        wtabT[1 * RSTRIDE + t] = __builtin_amdgcn_exp2f((xp[1] - x4) * LOG2E);
        wtabT[2 * RSTRIDE + t] = __builtin_amdgcn_exp2f((xp[2] - x4) * LOG2E);
        wtabT[3 * RSTRIDE + t] = __builtin_amdgcn_exp2f((xp[3] - x4) * LOG2E);
        csum += x4;
    }
    for (int i = tid; i < 576; i += 512) Gbuf[i] = LOG0;
    red[tid] = csum;
    __syncthreads();
    for (int off = 256; off > 0; off >>= 1) {
        if (tid < off) red[tid] += red[tid + off];
        __syncthreads();
    }
    // red[0] = C = sum over t of x_t[4]

    // ---------------- per-lane setup ----------------
    const int wbase = wave * 64 - 64;
    const int rel0 = 2 * lane;                 // 0..126; owned iff rel0 >= 64
    const int s0 = wbase + rel0, s1 = s0 + 1;
    const bool owned = (rel0 >= 64);

    const int i0 = (s0 >= 1 && s0 <= NS) ? seqs[b * NS + s0 - 1] : 0;
    const int i1 = (s1 >= 1 && s1 <= NS) ? seqs[b * NS + s1 - 1] : 0;
    const float* wrow0 = &wtabT[i0 * RSTRIDE];
    const float* wrow1 = &wtabT[i1 * RSTRIDE];

    float p0 = (s0 == 0) ? 1.f : 0.f;
    float p1 = (s1 == 0) ? 1.f : 0.f;
    float Lw  = 0.f;   // per-lane log2 offset
    float adj = 1.f;   // 2^(Lw_left - Lw_self), refreshed after every renorm/exchange

    // W0A already contains the adj factor (folded off the dependent chain).
#define STEP(W0A, W1) do {                    \
        const float sh = wave_shr1(p1);       \
        p1 = fmaf(p0, (W1), p1);              \
        p0 = fmaf(sh, (W0A), p0);             \
    } while (0)

#define QSTEP(WA, WB) do {                    \
        STEP(WA.x * adj, WB.x);               \
        STEP(WA.y * adj, WB.y);               \
        STEP(WA.z * adj, WB.z);               \
        STEP(WA.w * adj, WB.w);               \
    } while (0)

    // ---------------- main loop: 125 chunks of 16 steps ----------------
    for (int c = 0; c < 125; ++c) {
        // Issue the chunk's 8 ds_read_b128 as ONE batch. The group barrier
        // pins exactly 8 DS_READs here (soft directive: no global freeze,
        // unlike sched_barrier(0)); waitcnt pass then emits counted
        // lgkmcnt(7..) so later reads complete under boundary + compute.
        const int tb = c << 4;
        const float4 a0 = *reinterpret_cast<const float4*>(wrow0 + tb);
        const float4 a1 = *reinterpret_cast<const float4*>(wrow0 + tb + 4);
        const float4 a2 = *reinterpret_cast<const float4*>(wrow0 + tb + 8);
        const float4 a3 = *reinterpret_cast<const float4*>(wrow0 + tb + 12);
        const float4 b0 = *reinterpret_cast<const float4*>(wrow1 + tb);
        const float4 b1 = *reinterpret_cast<const float4*>(wrow1 + tb + 4);
        const float4 b2 = *reinterpret_cast<const float4*>(wrow1 + tb + 8);
        const float4 b3 = *reinterpret_cast<const float4*>(wrow1 + tb + 12);
        __builtin_amdgcn_sched_group_barrier(0x100 /*DS_READ*/, 8, 0);

        if (c > 0) {
            if ((c & 3) == 0) {
                // ---- cross-wave exchange every 64 steps (log2 domain) ----
                __syncthreads();
                if (owned) {
                    Gbuf[64 + s0] = (p0 > 0.f) ? __builtin_amdgcn_logf(p0) + Lw : LOG0;
                    Gbuf[64 + s1] = (p1 > 0.f) ? __builtin_amdgcn_logf(p1) + Lw : LOG0;
                }
                __syncthreads();
                const float g0 = Gbuf[64 + s0];
                const float g1 = Gbuf[64 + s1];
                const float ref = fmaxf(g0, g1);
                const bool alive = (ref > 0.5f * LOG0);
                // live states form a prefix of the window -> last live lane is
                // nearest-live-left for all dead lanes. Uniform mask -> scalar ops.
                const unsigned long long mk = __ballot(alive);
                float fb = 0.f;
                if (mk) {
                    const int lastlive = 63 - __builtin_clzll(mk);
                    fb = __int_as_float(
                        __builtin_amdgcn_readlane(__float_as_int(ref), lastlive));
                }
                Lw = alive ? ref : fb;
                p0 = __builtin_amdgcn_exp2f(g0 - Lw);   // dead: exp2(-1e30)=0
                p1 = __builtin_amdgcn_exp2f(g1 - Lw);
                const float Lwp = wave_shr1(Lw);        // lane 0: Lwp=0; its sh inflow is 0 anyway
                adj = __builtin_amdgcn_exp2f(fminf(Lwp - Lw, 100.f));
            } else {
                // ---- renorm only when some live lane leaves safe range ----
                const float m = fmaxf(p0, p1);
                const bool bad = (m > 1e12f) || (m > 0.f && m < 1e-12f);
                if (__any(bad)) {
                    // wave-uniform: ALL lanes renorm together, so every Lw
                    // that changes gets a matching adj refresh below.
                    if (m > 0.f) {
                        const float inv = __builtin_amdgcn_rcpf(m);
                        Lw += __builtin_amdgcn_logf(m); // v_log_f32 = log2
                        p0 *= inv; p1 *= inv;
                    }
                    const float Lwp = wave_shr1(Lw);
                    adj = __builtin_amdgcn_exp2f(fminf(Lwp - Lw, 100.f));
                }
                // skipped: no Lw changed anywhere in the wave -> adj still valid
            }
        }

        QSTEP(a0, b0);
        QSTEP(a1, b1);
        QSTEP(a2, b2);
        QSTEP(a3, b3);
    }
#undef QSTEP
#undef STEP

    // ---------------- final write-out ----------------
    __syncthreads();
    if (owned) {
        Gbuf[64 + s0] = (p0 > 0.f) ? __builtin_amdgcn_logf(p0) + Lw : LOG0;
        Gbuf[64 + s1] = (p1 > 0.f) ? __builtin_amdgcn_logf(p1) + Lw : LOG0;
    }
    __syncthreads();
    if (tid == 0) {
        const int sl = seqlens[b];
        out[b] = -(Gbuf[64 + sl] * LN2F + red[0]) * (1.0f / (float)NT);
    }
}

extern "C" void kernel_launch(void* const* d_in, const int* in_sizes, int n_in,
                              void* d_out, int out_size, void* d_ws, size_t ws_size,
                              hipStream_t stream) {
    const float* x       = (const float*)d_in[0];
    const int*   seqs    = (const int*)d_in[1];
    const int*   seqlens = (const int*)d_in[2];
    float*       out     = (float*)d_out;

    ctc_fwd_kernel<<<dim3(NB), dim3(512), 0, stream>>>(x, seqs, seqlens, out);
}

// Round 10
// 120.320 us; speedup vs baseline: 1.0100x; 1.0100x over previous
//
#include <hip/hip_runtime.h>

#define NT 2000
#define NB 256
#define NF 5
#define NS 500
#define LOG0   (-1e30f)
#define LOG2E  1.44269504088896340736f
#define LN2F   0.69314718055994530942f
#define RSTRIDE 2024   // wtabT row stride: >=2000, %4==0 (b128 align), %32==8 (banks disjoint)

// FINAL (revert to R6, the session's best verified kernel).
// One block per batch, 512 threads = 8 waves, 2 states/lane.
// Wave w spans states [64w-64, 64w+127]: lanes 0-31 = 64-state left halo
// (recomputed redundantly), lanes 32-63 = 64 owned states. Halo depth 64 =
// exchange period 64 (info moves right 1 state/step).
//
// Session ladder: 167us baseline -> 112us (DPP wave_shr1 replaces
// ds_bpermute __shfl_up on the serial chain) -> 75us (+XCD batch swizzle:
// FETCH 36MB->5.3MB) -> 69us (8 waves x 2 states: 2 waves/SIMD TLP).
// Probed and rejected: reg double-buffer (R2/R4: allocator overflow /
// carry-mov cost), f16 table (R5: cvt cost > read savings), load hoist +
// sched_group_barrier (R6/R7: compiler ignores, VGPR pinned at 24),
// 16-wave 1-state layout (R8/R9: inf -- catch-up adj factors can stack
// ~2^100 within one chunk without the 2-state frame anchor + renorm
// checkpoints; liveness is not lane-prefix under underflow guards).
//
// Exp-domain recurrence p[s] += p[s-1]*w_t[idx[s]] with PER-LANE log2
// scale Lw. Cross-lane handoff via DPP wave_shr:1 (lane 0 gets 0).
// adj = 2^(Lw_left-Lw_self) folded into the W0 operand off the chain.
// Conditional renorm every 16 steps (fires only when a live lane leaves
// [1e-12,1e12]; wave-uniform, adj stays valid when skipped). Cross-wave
// exchange (log2 domain via Gbuf) every 64 steps.
__device__ __forceinline__ float wave_shr1(float v) {
    // DPP wave_shr:1 (0x138): lane i reads lane i-1; bound_ctrl=1 -> lane 0 = 0.
    return __int_as_float(
        __builtin_amdgcn_mov_dpp(__float_as_int(v), 0x138, 0xf, 0xf, true));
}

__global__ __launch_bounds__(512, 1) void ctc_fwd_kernel(
    const float* __restrict__ x,        // (NT, NB, NF)
    const int*   __restrict__ seqs,     // (NB, NS)
    const int*   __restrict__ seqlens,  // (NB,)
    float*       __restrict__ out)      // (NB,)
{
    __shared__ __align__(16) float wtabT[4 * RSTRIDE];  // w[i][t] = exp(x_t[i]-x_t[4])
    __shared__ float Gbuf[576];                         // log2-domain exchange, idx = 64+s
    __shared__ float red[512];                          // stay-sum reduction

    // XCD-aware batch swizzle: hw round-robins blockIdx%8 across XCDs;
    // map so XCD k handles contiguous b in [32k, 32k+32) for L2 line sharing.
    const int b    = ((blockIdx.x & 7) << 5) | (blockIdx.x >> 3);
    const int tid  = threadIdx.x;
    const int wave = tid >> 6;
    const int lane = tid & 63;

    // ---------------- precompute: transposed weights + stay sum ----------------
    float csum = 0.f;
    for (int t = tid; t < NT; t += 512) {
        const float* xp = x + (size_t)t * (NB * NF) + b * NF;
        const float x4 = xp[4];
        wtabT[0 * RSTRIDE + t] = __builtin_amdgcn_exp2f((xp[0] - x4) * LOG2E);
        wtabT[1 * RSTRIDE + t] = __builtin_amdgcn_exp2f((xp[1] - x4) * LOG2E);
        wtabT[2 * RSTRIDE + t] = __builtin_amdgcn_exp2f((xp[2] - x4) * LOG2E);
        wtabT[3 * RSTRIDE + t] = __builtin_amdgcn_exp2f((xp[3] - x4) * LOG2E);
        csum += x4;
    }
    for (int i = tid; i < 576; i += 512) Gbuf[i] = LOG0;
    red[tid] = csum;
    __syncthreads();
    for (int off = 256; off > 0; off >>= 1) {
        if (tid < off) red[tid] += red[tid + off];
        __syncthreads();
    }
    // red[0] = C = sum over t of x_t[4]

    // ---------------- per-lane setup ----------------
    const int wbase = wave * 64 - 64;
    const int rel0 = 2 * lane;                 // 0..126; owned iff rel0 >= 64
    const int s0 = wbase + rel0, s1 = s0 + 1;
    const bool owned = (rel0 >= 64);

    const int i0 = (s0 >= 1 && s0 <= NS) ? seqs[b * NS + s0 - 1] : 0;
    const int i1 = (s1 >= 1 && s1 <= NS) ? seqs[b * NS + s1 - 1] : 0;
    const float* wrow0 = &wtabT[i0 * RSTRIDE];
    const float* wrow1 = &wtabT[i1 * RSTRIDE];

    float p0 = (s0 == 0) ? 1.f : 0.f;
    float p1 = (s1 == 0) ? 1.f : 0.f;
    float Lw  = 0.f;   // per-lane log2 offset
    float adj = 1.f;   // 2^(Lw_left - Lw_self), refreshed after every renorm/exchange

    // W0A already contains the adj factor (folded off the dependent chain).
#define STEP(W0A, W1) do {                    \
        const float sh = wave_shr1(p1);       \
        p1 = fmaf(p0, (W1), p1);              \
        p0 = fmaf(sh, (W0A), p0);             \
    } while (0)

#define QSTEP(WA, WB) do {                    \
        STEP(WA.x * adj, WB.x);               \
        STEP(WA.y * adj, WB.y);               \
        STEP(WA.z * adj, WB.z);               \
        STEP(WA.w * adj, WB.w);               \
    } while (0)

    // ---------------- main loop: 125 chunks of 16 steps ----------------
    for (int c = 0; c < 125; ++c) {
        // Issue the chunk's 8 ds_read_b128 first: their latency hides under
        // the boundary code below (renorm test / exchange).
        const int tb = c << 4;
        const float4 a0 = *reinterpret_cast<const float4*>(wrow0 + tb);
        const float4 a1 = *reinterpret_cast<const float4*>(wrow0 + tb + 4);
        const float4 a2 = *reinterpret_cast<const float4*>(wrow0 + tb + 8);
        const float4 a3 = *reinterpret_cast<const float4*>(wrow0 + tb + 12);
        const float4 b0 = *reinterpret_cast<const float4*>(wrow1 + tb);
        const float4 b1 = *reinterpret_cast<const float4*>(wrow1 + tb + 4);
        const float4 b2 = *reinterpret_cast<const float4*>(wrow1 + tb + 8);
        const float4 b3 = *reinterpret_cast<const float4*>(wrow1 + tb + 12);

        if (c > 0) {
            if ((c & 3) == 0) {
                // ---- cross-wave exchange every 64 steps (log2 domain) ----
                __syncthreads();
                if (owned) {
                    Gbuf[64 + s0] = (p0 > 0.f) ? __builtin_amdgcn_logf(p0) + Lw : LOG0;
                    Gbuf[64 + s1] = (p1 > 0.f) ? __builtin_amdgcn_logf(p1) + Lw : LOG0;
                }
                __syncthreads();
                const float g0 = Gbuf[64 + s0];
                const float g1 = Gbuf[64 + s1];
                const float ref = fmaxf(g0, g1);
                const bool alive = (ref > 0.5f * LOG0);
                // live states form a prefix of the window -> last live lane is
                // nearest-live-left for all dead lanes. Uniform mask -> scalar ops.
                const unsigned long long mk = __ballot(alive);
                float fb = 0.f;
                if (mk) {
                    const int lastlive = 63 - __builtin_clzll(mk);
                    fb = __int_as_float(
                        __builtin_amdgcn_readlane(__float_as_int(ref), lastlive));
                }
                Lw = alive ? ref : fb;
                p0 = __builtin_amdgcn_exp2f(g0 - Lw);   // dead: exp2(-1e30)=0
                p1 = __builtin_amdgcn_exp2f(g1 - Lw);
                const float Lwp = wave_shr1(Lw);        // lane 0: Lwp=0; its sh inflow is 0 anyway
                adj = __builtin_amdgcn_exp2f(fminf(Lwp - Lw, 100.f));
            } else {
                // ---- renorm only when some live lane leaves safe range ----
                const float m = fmaxf(p0, p1);
                const bool bad = (m > 1e12f) || (m > 0.f && m < 1e-12f);
                if (__any(bad)) {
                    // wave-uniform: ALL lanes renorm together, so every Lw
                    // that changes gets a matching adj refresh below.
                    if (m > 0.f) {
                        const float inv = __builtin_amdgcn_rcpf(m);
                        Lw += __builtin_amdgcn_logf(m); // v_log_f32 = log2
                        p0 *= inv; p1 *= inv;
                    }
                    const float Lwp = wave_shr1(Lw);
                    adj = __builtin_amdgcn_exp2f(fminf(Lwp - Lw, 100.f));
                }
                // skipped: no Lw changed anywhere in the wave -> adj still valid
            }
        }

        QSTEP(a0, b0);
        QSTEP(a1, b1);
        QSTEP(a2, b2);
        QSTEP(a3, b3);
    }
#undef QSTEP
#undef STEP

    // ---------------- final write-out ----------------
    __syncthreads();
    if (owned) {
        Gbuf[64 + s0] = (p0 > 0.f) ? __builtin_amdgcn_logf(p0) + Lw : LOG0;
        Gbuf[64 + s1] = (p1 > 0.f) ? __builtin_amdgcn_logf(p1) + Lw : LOG0;
    }
    __syncthreads();
    if (tid == 0) {
        const int sl = seqlens[b];
        out[b] = -(Gbuf[64 + sl] * LN2F + red[0]) * (1.0f / (float)NT);
    }
}

extern "C" void kernel_launch(void* const* d_in, const int* in_sizes, int n_in,
                              void* d_out, int out_size, void* d_ws, size_t ws_size,
                              hipStream_t stream) {
    const float* x       = (const float*)d_in[0];
    const int*   seqs    = (const int*)d_in[1];
    const int*   seqlens = (const int*)d_in[2];
    float*       out     = (float*)d_out;

    ctc_fwd_kernel<<<dim3(NB), dim3(512), 0, stream>>>(x, seqs, seqlens, out);
}